// Round 4
// baseline (3105.278 us; speedup 1.0000x reference)
//
#include <hip/hip_runtime.h>

typedef __bf16 bf16;
typedef bf16 bf16x8 __attribute__((ext_vector_type(8)));
typedef float f32x4 __attribute__((ext_vector_type(4)));

#define NBT 4096      // B*T = 8*512
#define NJ 21
#define NLF 86016     // NBT*NJ
#define DD 256
#define CONV_M 86352  // 168*514
#define SPAD 514
#define CROWS 86528   // 1 guard row + 86352 + overrun slack

// flags: 1=A_F32  2=OUT_F32(C32)  4=RELU  8=BNSS(sc/sh)  16=PADZ(conv layout)
//        32=LFOUT(remap conv row -> lf row)  bias!=null => +bias
__global__ __launch_bounds__(256, 2) void gemm_bf16(
    const void* __restrict__ Av, const bf16* __restrict__ Bt,
    float* __restrict__ C32, bf16* __restrict__ Cout,
    const float* __restrict__ bias, const float* __restrict__ sc,
    const float* __restrict__ sh, int M, int N, int K, int lda, int flags)
{
  __shared__ bf16 As[128][40];
  __shared__ bf16 Bs[128][40];
  const int tid = threadIdx.x;
  const long m0 = (long)blockIdx.y * 128;
  const int n0 = blockIdx.x * 128;
  const int wave = tid >> 6, lane = tid & 63;
  const int wm = (wave & 1) * 64, wn = (wave >> 1) * 64;
  const int lr = tid >> 1, lc = (tid & 1) * 16;
  const int frow = lane & 15, fkb = (lane >> 4) * 8;
  f32x4 acc[4][4] = {};
  for (int k0 = 0; k0 < K; k0 += 32) {
    if (flags & 1) {
      const float* ap = (const float*)Av + (m0 + lr) * (long)lda + (k0 + lc);
      bf16x8 t0, t1;
      #pragma unroll
      for (int u = 0; u < 8; u++) { t0[u] = (bf16)ap[u]; t1[u] = (bf16)ap[8 + u]; }
      *(bf16x8*)(&As[lr][lc])     = t0;
      *(bf16x8*)(&As[lr][lc + 8]) = t1;
    } else {
      const bf16* ap = (const bf16*)Av + (m0 + lr) * (long)lda + (k0 + lc);
      *(bf16x8*)(&As[lr][lc])     = *(const bf16x8*)(ap);
      *(bf16x8*)(&As[lr][lc + 8]) = *(const bf16x8*)(ap + 8);
    }
    const bf16* bp = Bt + (n0 + lr) * (long)K + (k0 + lc);
    *(bf16x8*)(&Bs[lr][lc])     = *(const bf16x8*)(bp);
    *(bf16x8*)(&Bs[lr][lc + 8]) = *(const bf16x8*)(bp + 8);
    __syncthreads();
    bf16x8 af[4], bg[4];
    #pragma unroll
    for (int i = 0; i < 4; i++) af[i] = *(const bf16x8*)(&As[wm + i * 16 + frow][fkb]);
    #pragma unroll
    for (int j = 0; j < 4; j++) bg[j] = *(const bf16x8*)(&Bs[wn + j * 16 + frow][fkb]);
    #pragma unroll
    for (int i = 0; i < 4; i++)
      #pragma unroll
      for (int j = 0; j < 4; j++)
        acc[i][j] = __builtin_amdgcn_mfma_f32_16x16x32_bf16(af[i], bg[j], acc[i][j], 0, 0, 0);
    __syncthreads();
  }
  const int col = lane & 15, rbase = (lane >> 4) * 4;
  #pragma unroll
  for (int i = 0; i < 4; i++) {
    #pragma unroll
    for (int j = 0; j < 4; j++) {
      const int nn = n0 + wn + j * 16 + col;
      #pragma unroll
      for (int r = 0; r < 4; r++) {
        const long mm = m0 + wm + i * 16 + rbase + r;
        if (mm >= M) continue;
        float v = acc[i][j][r];
        if (flags & 2) { C32[mm * (long)N + nn] = v; continue; }
        if (flags & 8) v = v * sc[nn] + sh[nn];
        else if (bias) v += bias[nn];
        if (flags & 4) v = fmaxf(v, 0.f);
        if (flags & 16) {
          const int s = (int)(mm % SPAD);
          if (s == 0 || s == SPAD - 1) v = 0.f;
          Cout[mm * (long)N + nn] = (bf16)v;
        } else if (flags & 32) {
          const long hj = mm / SPAD; const int s = (int)(mm - hj * SPAD);
          if (s == 0 || s == SPAD - 1) continue;
          const long b = hj / NJ; const int j2 = (int)(hj - b * NJ);
          const long dst = (b * 512 + (s - 1)) * NJ + j2;
          Cout[dst * (long)N + nn] = (bf16)v;
        } else {
          Cout[mm * (long)N + nn] = (bf16)v;
        }
      }
    }
  }
}

// ---------------- weight prep (f32 -> bf16) ----------------
__global__ void cvt_k(const float* __restrict__ s, bf16* __restrict__ d, long n) {
  long i = (long)blockIdx.x * 256 + threadIdx.x;
  if (i < n) d[i] = (bf16)s[i];
}
__global__ void prep_gatW(const float* __restrict__ W, bf16* __restrict__ Wt, int F) {
  long idx = (long)blockIdx.x * 256 + threadIdx.x;   // 256*F
  if (idx >= 256L * F) return;
  int n = (int)(idx / F), f = (int)(idx % F);
  Wt[idx] = (bf16)W[((long)(n >> 6) * F + f) * 64 + (n & 63)];
}
__global__ void prep_convw(const float* __restrict__ w, bf16* __restrict__ wp) {
  int idx = blockIdx.x * 256 + threadIdx.x;          // 256*768
  int n = idx / 768, k = idx % 768, tap = k >> 8, i = k & 255;
  wp[idx] = (bf16)w[(n * 256 + i) * 3 + tap];
}
__global__ void prep_out2(const float* __restrict__ w, bf16* __restrict__ wp) {
  int idx = blockIdx.x * 256 + threadIdx.x;          // 128*256
  wp[idx] = (idx < 63 * 256) ? (bf16)w[idx] : (bf16)0.f;
}
__global__ void prep_scsh(const float* __restrict__ cb, const float* __restrict__ g,
                          const float* __restrict__ be, const float* __restrict__ m,
                          const float* __restrict__ v, float* __restrict__ sc,
                          float* __restrict__ sh) {
  int c = threadIdx.x;
  float rs = rsqrtf(v[c] + 1e-5f) * g[c];
  sc[c] = rs; sh[c] = (cb[c] - m[c]) * rs + be[c];
}
__global__ void pad_zero(bf16* __restrict__ convIn) {
  int idx = blockIdx.x * 256 + threadIdx.x;          // 168*2*256
  int hj = idx >> 9, s = ((idx >> 8) & 1) ? (SPAD - 1) : 0, c = idx & 255;
  convIn[((long)hj * SPAD + s) * DD + c] = (bf16)0.f;
}
__global__ void zero_out(float* __restrict__ o, long n) {
  long i = (long)blockIdx.x * 256 + threadIdx.x;
  if (i < n) o[i] = 0.f;
}

// ---------------- GAT attention (per bt block; in-place safe) ----------------
__global__ __launch_bounds__(256) void gat_attn(
    const bf16* __restrict__ Wh, const float* __restrict__ a,
    const float* __restrict__ adj, bf16* __restrict__ out, int convMode)
{
  const int bt = blockIdx.x, tid = threadIdx.x;
  __shared__ float whs[NJ][DD];
  __shared__ float s1[4][NJ], s2[4][NJ];
  __shared__ float att[4][NJ][NJ];
  const long base = (long)bt * NJ * DD;
  for (int i = tid; i < NJ * DD; i += 256)
    whs[i >> 8][i & 255] = (float)Wh[base + i];
  __syncthreads();
  if (tid < 4 * NJ) {
    const int h = tid / NJ, i = tid % NJ;
    float x1 = 0.f, x2 = 0.f;
    for (int d = 0; d < 64; d++) {
      const float w = whs[i][h * 64 + d];
      x1 += w * a[h * 128 + d];
      x2 += w * a[h * 128 + 64 + d];
    }
    s1[h][i] = x1; s2[h][i] = x2;
  }
  __syncthreads();
  for (int idx = tid; idx < 4 * NJ * NJ; idx += 256) {
    const int h = idx / (NJ * NJ), r = idx % (NJ * NJ), i = r / NJ, j = r % NJ;
    float e = s1[h][i] + s2[h][j];
    e = e > 0.f ? e : 0.2f * e;
    att[h][i][j] = (adj[i * NJ + j] > 0.f) ? e : -9e15f;
  }
  __syncthreads();
  if (tid < 4 * NJ) {
    const int h = tid / NJ, i = tid % NJ;
    float mx = -3e38f;
    for (int j = 0; j < NJ; j++) mx = fmaxf(mx, att[h][i][j]);
    float sum = 0.f;
    for (int j = 0; j < NJ; j++) { const float ex = __expf(att[h][i][j] - mx); att[h][i][j] = ex; sum += ex; }
    const float inv = 1.f / sum;
    for (int j = 0; j < NJ; j++) att[h][i][j] *= inv;
  }
  __syncthreads();
  const int b = bt >> 9, t = bt & 511;
  for (int idx = tid; idx < NJ * DD; idx += 256) {
    const int i = idx >> 8, c = idx & 255, h = c >> 6;
    float s = 0.f;
    for (int j = 0; j < NJ; j++) s += att[h][i][j] * whs[j][c];
    s = s > 0.f ? s : (__expf(s) - 1.f);              // ELU
    const long row = convMode ? (((long)(b * NJ + i)) * SPAD + (t + 1)) : ((long)bt * NJ + i);
    out[row * DD + c] = (bf16)s;
  }
}

// ---------------- MHA core (per bt block; O may alias Q) ----------------
__global__ __launch_bounds__(256) void mha_core(
    const bf16* __restrict__ Q, const bf16* __restrict__ K,
    const bf16* __restrict__ V, bf16* __restrict__ O)
{
  const int bt = blockIdx.x, tid = threadIdx.x;
  __shared__ bf16 qs[NJ][DD], ks[NJ][DD], vs[NJ][DD];
  __shared__ float att[4][NJ][NJ];
  const long base = (long)bt * NJ * DD;
  for (int i = tid; i < NJ * DD; i += 256) {
    const int r = i >> 8, c = i & 255;
    qs[r][c] = Q[base + i]; ks[r][c] = K[base + i]; vs[r][c] = V[base + i];
  }
  __syncthreads();
  for (int idx = tid; idx < 4 * NJ * NJ; idx += 256) {
    const int h = idx / (NJ * NJ), r = idx % (NJ * NJ), i = r / NJ, j = r % NJ;
    float s = 0.f;
    for (int d = 0; d < 64; d++) s += (float)qs[i][h * 64 + d] * (float)ks[j][h * 64 + d];
    att[h][i][j] = s * 0.125f;
  }
  __syncthreads();
  if (tid < 4 * NJ) {
    const int h = tid / NJ, i = tid % NJ;
    float mx = -3e38f;
    for (int j = 0; j < NJ; j++) mx = fmaxf(mx, att[h][i][j]);
    float sum = 0.f;
    for (int j = 0; j < NJ; j++) { const float ex = __expf(att[h][i][j] - mx); att[h][i][j] = ex; sum += ex; }
    const float inv = 1.f / sum;
    for (int j = 0; j < NJ; j++) att[h][i][j] *= inv;
  }
  __syncthreads();
  for (int idx = tid; idx < NJ * DD; idx += 256) {
    const int i = idx >> 8, c = idx & 255, h = c >> 6;
    float s = 0.f;
    for (int j = 0; j < NJ; j++) s += att[h][i][j] * (float)vs[j][c];
    O[base + i * DD + c] = (bf16)s;
  }
}

// ---------------- residual + joint-mean pool ----------------
__global__ __launch_bounds__(256) void pool_kernel(
    const bf16* __restrict__ lf, const bf16* __restrict__ ao, bf16* __restrict__ o)
{
  const int bt = blockIdx.x, c = threadIdx.x;
  float s = 0.f;
  for (int j = 0; j < NJ; j++) {
    const long r = ((long)bt * NJ + j) * DD + c;
    s += (float)lf[r] + 0.5f * (float)ao[r];
  }
  o[(long)bt * DD + c] = (bf16)(s * (1.f / 21.f));
}

// ---------------- persistent LSTM layer ----------------
// Weights as 32 NAMED f32x4 (no alloca -> guaranteed VGPR residency; SROA
// runs before unroll, so an indexed array stays in scratch — measured R2/R3
// VGPR_Count=80 both rounds).
#define REP32(X) X(0) X(1) X(2) X(3) X(4) X(5) X(6) X(7) X(8) X(9) X(10) X(11) \
  X(12) X(13) X(14) X(15) X(16) X(17) X(18) X(19) X(20) X(21) X(22) X(23) \
  X(24) X(25) X(26) X(27) X(28) X(29) X(30) X(31)

__global__ __launch_bounds__(512, 2) void lstm_layer(
    const float* __restrict__ xw,
    const float* __restrict__ whhF, const float* __restrict__ whhB,
    const float* __restrict__ bihF, const float* __restrict__ bhhF,
    const float* __restrict__ bihB, const float* __restrict__ bhhB,
    bf16* __restrict__ outL, bf16* __restrict__ outR)
{
  const int wg = blockIdx.x;
  const int hand = wg >> 4, dir = (wg >> 3) & 1, b = wg & 7;
  const int tid = threadIdx.x;
  const float* whh = dir ? whhB : whhF;
#define WLOAD(i) const f32x4 w##i = *(const f32x4*)(whh + (long)tid * 128 + (i) * 4);
  REP32(WLOAD)
#undef WLOAD
  const float bias = (dir ? bihB : bihF)[tid] + (dir ? bhhB : bhhF)[tid];
  __shared__ float hs[128];
  __shared__ float gs[512];
  float c = 0.f;
  if (tid < 128) hs[tid] = 0.f;
  const float* xp = xw + (((long)(hand * 2 + dir)) * NBT + (long)b * 512) * 512;
  bf16* outp = hand ? outR : outL;
  float xv = xp[(long)(dir ? 511 : 0) * 512 + tid];   // prefetch step 0
  __syncthreads();
  for (int s = 0; s < 512; s++) {
    const int t = dir ? (511 - s) : s;
    const int tn = dir ? (510 - s) : (s + 1);
    float xnext = 0.f;
    if (s < 511) xnext = xp[(long)tn * 512 + tid];    // prefetch next step
    float gsum = xv + bias;
#define WDOT(i) { const f32x4 h4 = *(const f32x4*)(hs + (i) * 4); \
    gsum += w##i[0]*h4[0] + w##i[1]*h4[1] + w##i[2]*h4[2] + w##i[3]*h4[3]; }
    REP32(WDOT)
#undef WDOT
    gs[tid] = gsum;
    __syncthreads();
    if (tid < 128) {
      const float ig = gs[tid], fg = gs[tid + 128], gg = gs[tid + 256], og = gs[tid + 384];
      const float si = __builtin_amdgcn_rcpf(1.f + __expf(-ig));
      const float sf = __builtin_amdgcn_rcpf(1.f + __expf(-fg));
      const float so = __builtin_amdgcn_rcpf(1.f + __expf(-og));
      const float tg = 1.f - 2.f * __builtin_amdgcn_rcpf(1.f + __expf(2.f * gg));
      c = sf * c + si * tg;
      const float tc = 1.f - 2.f * __builtin_amdgcn_rcpf(1.f + __expf(2.f * c));
      const float h = so * tc;
      hs[tid] = h;
      outp[((long)b * 512 + t) * 256 + dir * 128 + tid] = (bf16)h;
    }
    __syncthreads();
    xv = xnext;
  }
}

// ---------------- final: +bias, *visibility ----------------
__global__ __launch_bounds__(256) void finalize_k(
    const float* __restrict__ y, const float* __restrict__ b2,
    const float* __restrict__ vis, float* __restrict__ out)
{
  const int idx = blockIdx.x * 256 + threadIdx.x;
  if (idx >= NBT * 63) return;
  const int c = idx % 63; const int bt = idx / 63;
  out[idx] = (y[(long)bt * 128 + c] + b2[c]) * vis[bt * 21 + (c / 3)];
}

extern "C" void kernel_launch(void* const* d_in, const int* in_sizes, int n_in,
                              void* d_out, int out_size, void* d_ws, size_t ws_size,
                              hipStream_t stream) {
  (void)in_sizes; (void)n_in;
  const float* feats[2] = { (const float*)d_in[0], (const float*)d_in[1] };
  const float* adj  = (const float*)d_in[2];
  const float* vis  = (const float*)d_in[3];
  const float* gW[2] = { (const float*)d_in[4], (const float*)d_in[6] };
  const float* ga[2] = { (const float*)d_in[5], (const float*)d_in[7] };
  const float* cw_[2] = { (const float*)d_in[8],  (const float*)d_in[10] };
  const float* cb_[2] = { (const float*)d_in[9],  (const float*)d_in[11] };
  const float* bng[2] = { (const float*)d_in[12], (const float*)d_in[16] };
  const float* bnb[2] = { (const float*)d_in[13], (const float*)d_in[17] };
  const float* bnm[2] = { (const float*)d_in[14], (const float*)d_in[18] };
  const float* bnv[2] = { (const float*)d_in[15], (const float*)d_in[19] };
  const float* wq = (const float*)d_in[20], *wk = (const float*)d_in[21];
  const float* wv = (const float*)d_in[22], *wo = (const float*)d_in[23];
  const float* bq = (const float*)d_in[24], *bk = (const float*)d_in[25];
  const float* bv = (const float*)d_in[26], *bo = (const float*)d_in[27];
  const float* Lwih[2][2] = { { (const float*)d_in[28], (const float*)d_in[32] },
                              { (const float*)d_in[36], (const float*)d_in[40] } };
  const float* Lwhh[2][2] = { { (const float*)d_in[29], (const float*)d_in[33] },
                              { (const float*)d_in[37], (const float*)d_in[41] } };
  const float* Lbih[2][2] = { { (const float*)d_in[30], (const float*)d_in[34] },
                              { (const float*)d_in[38], (const float*)d_in[42] } };
  const float* Lbhh[2][2] = { { (const float*)d_in[31], (const float*)d_in[35] },
                              { (const float*)d_in[39], (const float*)d_in[43] } };
  const float* o1w = (const float*)d_in[44], *o1b = (const float*)d_in[45];
  const float* o2w = (const float*)d_in[46], *o2b = (const float*)d_in[47];

  char* base = (char*)d_ws;
  size_t off = 0;
  auto alloc = [&](size_t b) { size_t r = off; off += (b + 1023) & ~(size_t)1023; return r; };
  const size_t SZ_LF  = (size_t)NLF * DD * 2;     // 44.04 MB
  const size_t SZ_CNV = (size_t)CROWS * DD * 2;   // 44.30 MB
  const size_t SZ_BT  = (size_t)NBT * DD * 2;     // 2.10 MB
  const size_t o_w1t = alloc((size_t)256 * 512 * 2);
  const size_t o_w2t = alloc((size_t)256 * 256 * 2);
  const size_t o_cw1 = alloc((size_t)256 * 768 * 2);
  const size_t o_cw2 = alloc((size_t)256 * 768 * 2);
  const size_t o_wq  = alloc((size_t)256 * 256 * 2);
  const size_t o_wk  = alloc((size_t)256 * 256 * 2);
  const size_t o_wv  = alloc((size_t)256 * 256 * 2);
  const size_t o_wo  = alloc((size_t)256 * 256 * 2);
  const size_t o_o1w = alloc((size_t)256 * 256 * 2);
  const size_t o_o2p = alloc((size_t)128 * 256 * 2);
  const size_t o_lw0 = alloc((size_t)512 * 256 * 2);
  const size_t o_lw1 = alloc((size_t)512 * 256 * 2);
  const size_t o_lw2 = alloc((size_t)512 * 256 * 2);
  const size_t o_lw3 = alloc((size_t)512 * 256 * 2);
  const size_t o_ss  = alloc((size_t)4 * 256 * 4);
  const size_t o_B1  = alloc(SZ_LF);
  const size_t o_B2  = alloc(SZ_CNV);
  const size_t o_B3  = alloc(SZ_CNV);
  const size_t o_lfL = alloc(SZ_LF);
  const size_t o_lfR = alloc(SZ_LF);
  const size_t o_le  = alloc(SZ_BT);
  const size_t o_re  = alloc(SZ_BT);
  const size_t o_h1L = alloc(SZ_BT);
  const size_t o_h1R = alloc(SZ_BT);
  const size_t o_hoL = alloc(SZ_BT);
  const size_t o_hoR = alloc(SZ_BT);
  const size_t o_t1  = alloc(SZ_BT);
  const size_t o_y32 = alloc((size_t)NBT * 128 * 4);
  const size_t NEED = off;
  if (ws_size < NEED) {   // graceful diagnostic: zero output, clean absmax-fail
    zero_out<<<(out_size + 255) / 256, 256, 0, stream>>>((float*)d_out, out_size);
    return;
  }
  auto P = [&](size_t o_) { return (void*)(base + o_); };

  auto gemm = [&](const void* A, const void* Bt, void* c32, void* co,
                  const void* bias_, const void* sc_, const void* sh_,
                  long M, int N, int K, int lda, int flags) {
    dim3 g((unsigned)(N / 128), (unsigned)((M + 127) / 128));
    gemm_bf16<<<g, 256, 0, stream>>>(A, (const bf16*)Bt, (float*)c32, (bf16*)co,
                                     (const float*)bias_, (const float*)sc_,
                                     (const float*)sh_, (int)M, N, K, lda, flags);
  };
  auto cvt = [&](const float* s, void* d, long n) {
    cvt_k<<<(unsigned)((n + 255) / 256), 256, 0, stream>>>(s, (bf16*)d, n);
  };

  // ---- weight prep ----
  prep_gatW<<<512, 256, 0, stream>>>(gW[0], (bf16*)P(o_w1t), 512);
  prep_gatW<<<256, 256, 0, stream>>>(gW[1], (bf16*)P(o_w2t), 256);
  prep_convw<<<768, 256, 0, stream>>>(cw_[0], (bf16*)P(o_cw1));
  prep_convw<<<768, 256, 0, stream>>>(cw_[1], (bf16*)P(o_cw2));
  cvt(wq, P(o_wq), 65536); cvt(wk, P(o_wk), 65536);
  cvt(wv, P(o_wv), 65536); cvt(wo, P(o_wo), 65536);
  cvt(o1w, P(o_o1w), 65536);
  cvt(Lwih[0][0], P(o_lw0), 131072); cvt(Lwih[0][1], P(o_lw1), 131072);
  cvt(Lwih[1][0], P(o_lw2), 131072); cvt(Lwih[1][1], P(o_lw3), 131072);
  prep_out2<<<128, 256, 0, stream>>>(o2w, (bf16*)P(o_o2p));
  float* sc1 = (float*)P(o_ss); float* sh1 = sc1 + 256;
  float* sc2 = sh1 + 256;       float* sh2 = sc2 + 256;
  prep_scsh<<<1, 256, 0, stream>>>(cb_[0], bng[0], bnb[0], bnm[0], bnv[0], sc1, sh1);
  prep_scsh<<<1, 256, 0, stream>>>(cb_[1], bng[1], bnb[1], bnm[1], bnv[1], sc2, sh2);

  bf16* B1 = (bf16*)P(o_B1);
  bf16* B2 = (bf16*)P(o_B2);   // guard row at row 0; conv space = B2+DD
  bf16* B3 = (bf16*)P(o_B3);
  bf16* lfb[2] = { (bf16*)P(o_lfL), (bf16*)P(o_lfR) };

  // ---- per-hand: GAT x2 -> conv x2 -> lf ----
  for (int hd = 0; hd < 2; hd++) {
    gemm(feats[hd], P(o_w1t), nullptr, B1, nullptr, nullptr, nullptr,
         NLF, 256, 512, 512, 1);                                   // A_F32
    gat_attn<<<NBT, 256, 0, stream>>>(B1, ga[0], adj, B1, 0);      // in-place
    gemm(B1, P(o_w2t), nullptr, B2, nullptr, nullptr, nullptr,
         NLF, 256, 256, 256, 0);
    pad_zero<<<336, 256, 0, stream>>>(B3 + DD);
    gat_attn<<<NBT, 256, 0, stream>>>(B2, ga[1], adj, B3 + DD, 1); // conv layout
    // conv1: single GEMM K=768 over 3 contiguous rows, fused BN+ReLU+padzero
    gemm(B3, P(o_cw1), nullptr, B2 + DD, nullptr, sc1, sh1,
         CONV_M, 256, 768, 256, 8 | 4 | 16);
    // conv2: fused BN+ReLU, write straight to lf layout
    gemm(B2, P(o_cw2), nullptr, lfb[hd], nullptr, sc2, sh2,
         CONV_M, 256, 768, 256, 8 | 4 | 32);
  }

  // ---- cross-hand MHA ----
  // pass1 a_l2r: q=lf_L, k/v=lf_R
  gemm(lfb[0], P(o_wq), nullptr, B1, bq, nullptr, nullptr, NLF, 256, 256, 256, 0);
  gemm(lfb[1], P(o_wk), nullptr, B2, bk, nullptr, nullptr, NLF, 256, 256, 256, 0);
  gemm(lfb[1], P(o_wv), nullptr, B3, bv, nullptr, nullptr, NLF, 256, 256, 256, 0);
  mha_core<<<NBT, 256, 0, stream>>>(B1, B2, B3, B1);               // O in-place
  gemm(B1, P(o_wo), nullptr, B2, bo, nullptr, nullptr, NLF, 256, 256, 256, 0);
  pool_kernel<<<NBT, 256, 0, stream>>>(lfb[1], B2, (bf16*)P(o_re)); // re = rf+0.5*a_l2r
  // pass2 a_r2l: q=lf_R, k/v=lf_L
  gemm(lfb[1], P(o_wq), nullptr, B1, bq, nullptr, nullptr, NLF, 256, 256, 256, 0);
  gemm(lfb[0], P(o_wk), nullptr, B3, bk, nullptr, nullptr, NLF, 256, 256, 256, 0);
  gemm(lfb[0], P(o_wv), nullptr, B2, bv, nullptr, nullptr, NLF, 256, 256, 256, 0);
  mha_core<<<NBT, 256, 0, stream>>>(B1, B3, B2, B1);
  gemm(B1, P(o_wo), nullptr, B3, bo, nullptr, nullptr, NLF, 256, 256, 256, 0);
  pool_kernel<<<NBT, 256, 0, stream>>>(lfb[0], B3, (bf16*)P(o_le)); // le = lf+0.5*a_r2l

  // ---- BiLSTM (xw aliases B2 region: 33.5 MB f32) ----
  float* xw = (float*)P(o_B2);
  auto xslot = [&](int h_, int d_) { return (void*)(xw + ((size_t)(h_ * 2 + d_)) * NBT * 512); };
  gemm(P(o_le), P(o_lw0), xslot(0, 0), nullptr, nullptr, nullptr, nullptr, NBT, 512, 256, 256, 2);
  gemm(P(o_le), P(o_lw1), xslot(0, 1), nullptr, nullptr, nullptr, nullptr, NBT, 512, 256, 256, 2);
  gemm(P(o_re), P(o_lw0), xslot(1, 0), nullptr, nullptr, nullptr, nullptr, NBT, 512, 256, 256, 2);
  gemm(P(o_re), P(o_lw1), xslot(1, 1), nullptr, nullptr, nullptr, nullptr, NBT, 512, 256, 256, 2);
  lstm_layer<<<32, 512, 0, stream>>>(xw, Lwhh[0][0], Lwhh[0][1],
      Lbih[0][0], Lbhh[0][0], Lbih[0][1], Lbhh[0][1],
      (bf16*)P(o_h1L), (bf16*)P(o_h1R));
  gemm(P(o_h1L), P(o_lw2), xslot(0, 0), nullptr, nullptr, nullptr, nullptr, NBT, 512, 256, 256, 2);
  gemm(P(o_h1L), P(o_lw3), xslot(0, 1), nullptr, nullptr, nullptr, nullptr, NBT, 512, 256, 256, 2);
  gemm(P(o_h1R), P(o_lw2), xslot(1, 0), nullptr, nullptr, nullptr, nullptr, NBT, 512, 256, 256, 2);
  gemm(P(o_h1R), P(o_lw3), xslot(1, 1), nullptr, nullptr, nullptr, nullptr, NBT, 512, 256, 256, 2);
  lstm_layer<<<32, 512, 0, stream>>>(xw, Lwhh[1][0], Lwhh[1][1],
      Lbih[1][0], Lbhh[1][0], Lbih[1][1], Lbhh[1][1],
      (bf16*)P(o_hoL), (bf16*)P(o_hoR));

  // ---- heads + visibility ----
  for (int hd = 0; hd < 2; hd++) {
    const void* hin = hd ? P(o_hoR) : P(o_hoL);
    gemm(hin, P(o_o1w), nullptr, P(o_t1), o1b, nullptr, nullptr, NBT, 256, 256, 256, 4);
    gemm(P(o_t1), P(o_o2p), P(o_y32), nullptr, nullptr, nullptr, nullptr, NBT, 128, 256, 256, 2);
    finalize_k<<<(NBT * 63 + 255) / 256, 256, 0, stream>>>(
        (const float*)P(o_y32), o2b, vis, (float*)d_out + (size_t)hd * NBT * 63);
  }
}

// Round 5
// 2998.451 us; speedup vs baseline: 1.0356x; 1.0356x over previous
//
#include <hip/hip_runtime.h>

typedef __bf16 bf16;
typedef bf16 bf16x8 __attribute__((ext_vector_type(8)));
typedef float f32x4 __attribute__((ext_vector_type(4)));

#define NBT 4096      // B*T = 8*512
#define NJ 21
#define NLF 86016     // NBT*NJ
#define DD 256
#define CONV_M 86352  // 168*514
#define SPAD 514
#define CROWS 86528   // 1 guard row + 86352 + overrun slack

// flags: 1=A_F32  2=OUT_F32(C32)  4=RELU  8=BNSS(sc/sh)  16=PADZ(conv layout)
//        32=LFOUT(remap conv row -> lf row)  bias!=null => +bias
__global__ __launch_bounds__(256, 2) void gemm_bf16(
    const void* __restrict__ Av, const bf16* __restrict__ Bt,
    float* __restrict__ C32, bf16* __restrict__ Cout,
    const float* __restrict__ bias, const float* __restrict__ sc,
    const float* __restrict__ sh, int M, int N, int K, int lda, int flags)
{
  __shared__ bf16 As[128][40];
  __shared__ bf16 Bs[128][40];
  const int tid = threadIdx.x;
  const long m0 = (long)blockIdx.y * 128;
  const int n0 = blockIdx.x * 128;
  const int wave = tid >> 6, lane = tid & 63;
  const int wm = (wave & 1) * 64, wn = (wave >> 1) * 64;
  const int lr = tid >> 1, lc = (tid & 1) * 16;
  const int frow = lane & 15, fkb = (lane >> 4) * 8;
  f32x4 acc[4][4] = {};
  for (int k0 = 0; k0 < K; k0 += 32) {
    if (flags & 1) {
      const float* ap = (const float*)Av + (m0 + lr) * (long)lda + (k0 + lc);
      bf16x8 t0, t1;
      #pragma unroll
      for (int u = 0; u < 8; u++) { t0[u] = (bf16)ap[u]; t1[u] = (bf16)ap[8 + u]; }
      *(bf16x8*)(&As[lr][lc])     = t0;
      *(bf16x8*)(&As[lr][lc + 8]) = t1;
    } else {
      const bf16* ap = (const bf16*)Av + (m0 + lr) * (long)lda + (k0 + lc);
      *(bf16x8*)(&As[lr][lc])     = *(const bf16x8*)(ap);
      *(bf16x8*)(&As[lr][lc + 8]) = *(const bf16x8*)(ap + 8);
    }
    const bf16* bp = Bt + (n0 + lr) * (long)K + (k0 + lc);
    *(bf16x8*)(&Bs[lr][lc])     = *(const bf16x8*)(bp);
    *(bf16x8*)(&Bs[lr][lc + 8]) = *(const bf16x8*)(bp + 8);
    __syncthreads();
    bf16x8 af[4], bg[4];
    #pragma unroll
    for (int i = 0; i < 4; i++) af[i] = *(const bf16x8*)(&As[wm + i * 16 + frow][fkb]);
    #pragma unroll
    for (int j = 0; j < 4; j++) bg[j] = *(const bf16x8*)(&Bs[wn + j * 16 + frow][fkb]);
    #pragma unroll
    for (int i = 0; i < 4; i++)
      #pragma unroll
      for (int j = 0; j < 4; j++)
        acc[i][j] = __builtin_amdgcn_mfma_f32_16x16x32_bf16(af[i], bg[j], acc[i][j], 0, 0, 0);
    __syncthreads();
  }
  const int col = lane & 15, rbase = (lane >> 4) * 4;
  #pragma unroll
  for (int i = 0; i < 4; i++) {
    #pragma unroll
    for (int j = 0; j < 4; j++) {
      const int nn = n0 + wn + j * 16 + col;
      #pragma unroll
      for (int r = 0; r < 4; r++) {
        const long mm = m0 + wm + i * 16 + rbase + r;
        if (mm >= M) continue;
        float v = acc[i][j][r];
        if (flags & 2) { C32[mm * (long)N + nn] = v; continue; }
        if (flags & 8) v = v * sc[nn] + sh[nn];
        else if (bias) v += bias[nn];
        if (flags & 4) v = fmaxf(v, 0.f);
        if (flags & 16) {
          const int s = (int)(mm % SPAD);
          if (s == 0 || s == SPAD - 1) v = 0.f;
          Cout[mm * (long)N + nn] = (bf16)v;
        } else if (flags & 32) {
          const long hj = mm / SPAD; const int s = (int)(mm - hj * SPAD);
          if (s == 0 || s == SPAD - 1) continue;
          const long b = hj / NJ; const int j2 = (int)(hj - b * NJ);
          const long dst = (b * 512 + (s - 1)) * NJ + j2;
          Cout[dst * (long)N + nn] = (bf16)v;
        } else {
          Cout[mm * (long)N + nn] = (bf16)v;
        }
      }
    }
  }
}

// ---------------- weight prep (f32 -> bf16) ----------------
__global__ void cvt_k(const float* __restrict__ s, bf16* __restrict__ d, long n) {
  long i = (long)blockIdx.x * 256 + threadIdx.x;
  if (i < n) d[i] = (bf16)s[i];
}
__global__ void prep_gatW(const float* __restrict__ W, bf16* __restrict__ Wt, int F) {
  long idx = (long)blockIdx.x * 256 + threadIdx.x;   // 256*F
  if (idx >= 256L * F) return;
  int n = (int)(idx / F), f = (int)(idx % F);
  Wt[idx] = (bf16)W[((long)(n >> 6) * F + f) * 64 + (n & 63)];
}
__global__ void prep_convw(const float* __restrict__ w, bf16* __restrict__ wp) {
  int idx = blockIdx.x * 256 + threadIdx.x;          // 256*768
  int n = idx / 768, k = idx % 768, tap = k >> 8, i = k & 255;
  wp[idx] = (bf16)w[(n * 256 + i) * 3 + tap];
}
__global__ void prep_out2(const float* __restrict__ w, bf16* __restrict__ wp) {
  int idx = blockIdx.x * 256 + threadIdx.x;          // 128*256
  wp[idx] = (idx < 63 * 256) ? (bf16)w[idx] : (bf16)0.f;
}
__global__ void prep_scsh(const float* __restrict__ cb, const float* __restrict__ g,
                          const float* __restrict__ be, const float* __restrict__ m,
                          const float* __restrict__ v, float* __restrict__ sc,
                          float* __restrict__ sh) {
  int c = threadIdx.x;
  float rs = rsqrtf(v[c] + 1e-5f) * g[c];
  sc[c] = rs; sh[c] = (cb[c] - m[c]) * rs + be[c];
}
__global__ void pad_zero(bf16* __restrict__ convIn) {
  int idx = blockIdx.x * 256 + threadIdx.x;          // 168*2*256
  int hj = idx >> 9, s = ((idx >> 8) & 1) ? (SPAD - 1) : 0, c = idx & 255;
  convIn[((long)hj * SPAD + s) * DD + c] = (bf16)0.f;
}
__global__ void zero_out(float* __restrict__ o, long n) {
  long i = (long)blockIdx.x * 256 + threadIdx.x;
  if (i < n) o[i] = 0.f;
}

// ---------------- GAT attention (per bt block; in-place safe) ----------------
__global__ __launch_bounds__(256) void gat_attn(
    const bf16* __restrict__ Wh, const float* __restrict__ a,
    const float* __restrict__ adj, bf16* __restrict__ out, int convMode)
{
  const int bt = blockIdx.x, tid = threadIdx.x;
  __shared__ float whs[NJ][DD];
  __shared__ float s1[4][NJ], s2[4][NJ];
  __shared__ float att[4][NJ][NJ];
  const long base = (long)bt * NJ * DD;
  for (int i = tid; i < NJ * DD; i += 256)
    whs[i >> 8][i & 255] = (float)Wh[base + i];
  __syncthreads();
  if (tid < 4 * NJ) {
    const int h = tid / NJ, i = tid % NJ;
    float x1 = 0.f, x2 = 0.f;
    for (int d = 0; d < 64; d++) {
      const float w = whs[i][h * 64 + d];
      x1 += w * a[h * 128 + d];
      x2 += w * a[h * 128 + 64 + d];
    }
    s1[h][i] = x1; s2[h][i] = x2;
  }
  __syncthreads();
  for (int idx = tid; idx < 4 * NJ * NJ; idx += 256) {
    const int h = idx / (NJ * NJ), r = idx % (NJ * NJ), i = r / NJ, j = r % NJ;
    float e = s1[h][i] + s2[h][j];
    e = e > 0.f ? e : 0.2f * e;
    att[h][i][j] = (adj[i * NJ + j] > 0.f) ? e : -9e15f;
  }
  __syncthreads();
  if (tid < 4 * NJ) {
    const int h = tid / NJ, i = tid % NJ;
    float mx = -3e38f;
    for (int j = 0; j < NJ; j++) mx = fmaxf(mx, att[h][i][j]);
    float sum = 0.f;
    for (int j = 0; j < NJ; j++) { const float ex = __expf(att[h][i][j] - mx); att[h][i][j] = ex; sum += ex; }
    const float inv = 1.f / sum;
    for (int j = 0; j < NJ; j++) att[h][i][j] *= inv;
  }
  __syncthreads();
  const int b = bt >> 9, t = bt & 511;
  for (int idx = tid; idx < NJ * DD; idx += 256) {
    const int i = idx >> 8, c = idx & 255, h = c >> 6;
    float s = 0.f;
    for (int j = 0; j < NJ; j++) s += att[h][i][j] * whs[j][c];
    s = s > 0.f ? s : (__expf(s) - 1.f);              // ELU
    const long row = convMode ? (((long)(b * NJ + i)) * SPAD + (t + 1)) : ((long)bt * NJ + i);
    out[row * DD + c] = (bf16)s;
  }
}

// ---------------- MHA core (per bt block; O may alias Q) ----------------
__global__ __launch_bounds__(256) void mha_core(
    const bf16* __restrict__ Q, const bf16* __restrict__ K,
    const bf16* __restrict__ V, bf16* __restrict__ O)
{
  const int bt = blockIdx.x, tid = threadIdx.x;
  __shared__ bf16 qs[NJ][DD], ks[NJ][DD], vs[NJ][DD];
  __shared__ float att[4][NJ][NJ];
  const long base = (long)bt * NJ * DD;
  for (int i = tid; i < NJ * DD; i += 256) {
    const int r = i >> 8, c = i & 255;
    qs[r][c] = Q[base + i]; ks[r][c] = K[base + i]; vs[r][c] = V[base + i];
  }
  __syncthreads();
  for (int idx = tid; idx < 4 * NJ * NJ; idx += 256) {
    const int h = idx / (NJ * NJ), r = idx % (NJ * NJ), i = r / NJ, j = r % NJ;
    float s = 0.f;
    for (int d = 0; d < 64; d++) s += (float)qs[i][h * 64 + d] * (float)ks[j][h * 64 + d];
    att[h][i][j] = s * 0.125f;
  }
  __syncthreads();
  if (tid < 4 * NJ) {
    const int h = tid / NJ, i = tid % NJ;
    float mx = -3e38f;
    for (int j = 0; j < NJ; j++) mx = fmaxf(mx, att[h][i][j]);
    float sum = 0.f;
    for (int j = 0; j < NJ; j++) { const float ex = __expf(att[h][i][j] - mx); att[h][i][j] = ex; sum += ex; }
    const float inv = 1.f / sum;
    for (int j = 0; j < NJ; j++) att[h][i][j] *= inv;
  }
  __syncthreads();
  for (int idx = tid; idx < NJ * DD; idx += 256) {
    const int i = idx >> 8, c = idx & 255, h = c >> 6;
    float s = 0.f;
    for (int j = 0; j < NJ; j++) s += att[h][i][j] * (float)vs[j][c];
    O[base + i * DD + c] = (bf16)s;
  }
}

// ---------------- residual + joint-mean pool ----------------
__global__ __launch_bounds__(256) void pool_kernel(
    const bf16* __restrict__ lf, const bf16* __restrict__ ao, bf16* __restrict__ o)
{
  const int bt = blockIdx.x, c = threadIdx.x;
  float s = 0.f;
  for (int j = 0; j < NJ; j++) {
    const long r = ((long)bt * NJ + j) * DD + c;
    s += (float)lf[r] + 0.5f * (float)ao[r];
  }
  o[(long)bt * DD + c] = (bf16)(s * (1.f / 21.f));
}

// ---------------- persistent LSTM layer ----------------
// R2/R3/R4 post-mortem: VGPR_Count stayed 80 — the allocator REMATERIALIZES
// the loop-invariant weight loads (re-reading 512B/thread/step via L1,
// ~262KB/step/CU = the measured ~3000cyc/step) to chase occupancy.
// Two levers: (a) waves_per_eu(2,2) — max occupancy 2 removes the incentive;
// (b) per-iteration empty asm "+v" ties — make reload illegal.
#define REP32(X) X(0) X(1) X(2) X(3) X(4) X(5) X(6) X(7) X(8) X(9) X(10) X(11) \
  X(12) X(13) X(14) X(15) X(16) X(17) X(18) X(19) X(20) X(21) X(22) X(23) \
  X(24) X(25) X(26) X(27) X(28) X(29) X(30) X(31)

__global__ __attribute__((amdgpu_flat_work_group_size(512, 512),
                          amdgpu_waves_per_eu(2, 2)))
void lstm_layer(
    const float* __restrict__ xw,
    const float* __restrict__ whhF, const float* __restrict__ whhB,
    const float* __restrict__ bihF, const float* __restrict__ bhhF,
    const float* __restrict__ bihB, const float* __restrict__ bhhB,
    bf16* __restrict__ outL, bf16* __restrict__ outR)
{
  const int wg = blockIdx.x;
  const int hand = wg >> 4, dir = (wg >> 3) & 1, b = wg & 7;
  const int tid = threadIdx.x;
  const float* whh = dir ? whhB : whhF;
#define WLOAD(i) f32x4 w##i = *(const f32x4*)(whh + (long)tid * 128 + (i) * 4);
  REP32(WLOAD)
#undef WLOAD
  const float bias = (dir ? bihB : bihF)[tid] + (dir ? bhhB : bhhF)[tid];
  __shared__ float hs[128];
  __shared__ float gs[512];
  float c = 0.f;
  if (tid < 128) hs[tid] = 0.f;
  const float* xp = xw + (((long)(hand * 2 + dir)) * NBT + (long)b * 512) * 512;
  bf16* outp = hand ? outR : outL;
  float xv = xp[(long)(dir ? 511 : 0) * 512 + tid];   // prefetch step 0
  __syncthreads();
  for (int s = 0; s < 512; s++) {
    // force all 32 weight vectors to be register-resident this iteration
#define WKEEP(i) asm volatile("" : "+v"(w##i));
    REP32(WKEEP)
#undef WKEEP
    const int t = dir ? (511 - s) : s;
    const int tn = dir ? (510 - s) : (s + 1);
    float xnext = 0.f;
    if (s < 511) xnext = xp[(long)tn * 512 + tid];    // prefetch next step
    float gsum = xv + bias;
#define WDOT(i) { const f32x4 h4 = *(const f32x4*)(hs + (i) * 4); \
    gsum += w##i[0]*h4[0] + w##i[1]*h4[1] + w##i[2]*h4[2] + w##i[3]*h4[3]; }
    REP32(WDOT)
#undef WDOT
    gs[tid] = gsum;
    __syncthreads();
    if (tid < 128) {
      const float ig = gs[tid], fg = gs[tid + 128], gg = gs[tid + 256], og = gs[tid + 384];
      const float si = __builtin_amdgcn_rcpf(1.f + __expf(-ig));
      const float sf = __builtin_amdgcn_rcpf(1.f + __expf(-fg));
      const float so = __builtin_amdgcn_rcpf(1.f + __expf(-og));
      const float tg = 1.f - 2.f * __builtin_amdgcn_rcpf(1.f + __expf(2.f * gg));
      c = sf * c + si * tg;
      const float tc = 1.f - 2.f * __builtin_amdgcn_rcpf(1.f + __expf(2.f * c));
      const float h = so * tc;
      hs[tid] = h;
      outp[((long)b * 512 + t) * 256 + dir * 128 + tid] = (bf16)h;
    }
    __syncthreads();
    xv = xnext;
  }
}

// ---------------- final: +bias, *visibility ----------------
__global__ __launch_bounds__(256) void finalize_k(
    const float* __restrict__ y, const float* __restrict__ b2,
    const float* __restrict__ vis, float* __restrict__ out)
{
  const int idx = blockIdx.x * 256 + threadIdx.x;
  if (idx >= NBT * 63) return;
  const int c = idx % 63; const int bt = idx / 63;
  out[idx] = (y[(long)bt * 128 + c] + b2[c]) * vis[bt * 21 + (c / 3)];
}

extern "C" void kernel_launch(void* const* d_in, const int* in_sizes, int n_in,
                              void* d_out, int out_size, void* d_ws, size_t ws_size,
                              hipStream_t stream) {
  (void)in_sizes; (void)n_in;
  const float* feats[2] = { (const float*)d_in[0], (const float*)d_in[1] };
  const float* adj  = (const float*)d_in[2];
  const float* vis  = (const float*)d_in[3];
  const float* gW[2] = { (const float*)d_in[4], (const float*)d_in[6] };
  const float* ga[2] = { (const float*)d_in[5], (const float*)d_in[7] };
  const float* cw_[2] = { (const float*)d_in[8],  (const float*)d_in[10] };
  const float* cb_[2] = { (const float*)d_in[9],  (const float*)d_in[11] };
  const float* bng[2] = { (const float*)d_in[12], (const float*)d_in[16] };
  const float* bnb[2] = { (const float*)d_in[13], (const float*)d_in[17] };
  const float* bnm[2] = { (const float*)d_in[14], (const float*)d_in[18] };
  const float* bnv[2] = { (const float*)d_in[15], (const float*)d_in[19] };
  const float* wq = (const float*)d_in[20], *wk = (const float*)d_in[21];
  const float* wv = (const float*)d_in[22], *wo = (const float*)d_in[23];
  const float* bq = (const float*)d_in[24], *bk = (const float*)d_in[25];
  const float* bv = (const float*)d_in[26], *bo = (const float*)d_in[27];
  const float* Lwih[2][2] = { { (const float*)d_in[28], (const float*)d_in[32] },
                              { (const float*)d_in[36], (const float*)d_in[40] } };
  const float* Lwhh[2][2] = { { (const float*)d_in[29], (const float*)d_in[33] },
                              { (const float*)d_in[37], (const float*)d_in[41] } };
  const float* Lbih[2][2] = { { (const float*)d_in[30], (const float*)d_in[34] },
                              { (const float*)d_in[38], (const float*)d_in[42] } };
  const float* Lbhh[2][2] = { { (const float*)d_in[31], (const float*)d_in[35] },
                              { (const float*)d_in[39], (const float*)d_in[43] } };
  const float* o1w = (const float*)d_in[44], *o1b = (const float*)d_in[45];
  const float* o2w = (const float*)d_in[46], *o2b = (const float*)d_in[47];

  char* base = (char*)d_ws;
  size_t off = 0;
  auto alloc = [&](size_t b) { size_t r = off; off += (b + 1023) & ~(size_t)1023; return r; };
  const size_t SZ_LF  = (size_t)NLF * DD * 2;     // 44.04 MB
  const size_t SZ_CNV = (size_t)CROWS * DD * 2;   // 44.30 MB
  const size_t SZ_BT  = (size_t)NBT * DD * 2;     // 2.10 MB
  const size_t o_w1t = alloc((size_t)256 * 512 * 2);
  const size_t o_w2t = alloc((size_t)256 * 256 * 2);
  const size_t o_cw1 = alloc((size_t)256 * 768 * 2);
  const size_t o_cw2 = alloc((size_t)256 * 768 * 2);
  const size_t o_wq  = alloc((size_t)256 * 256 * 2);
  const size_t o_wk  = alloc((size_t)256 * 256 * 2);
  const size_t o_wv  = alloc((size_t)256 * 256 * 2);
  const size_t o_wo  = alloc((size_t)256 * 256 * 2);
  const size_t o_o1w = alloc((size_t)256 * 256 * 2);
  const size_t o_o2p = alloc((size_t)128 * 256 * 2);
  const size_t o_lw0 = alloc((size_t)512 * 256 * 2);
  const size_t o_lw1 = alloc((size_t)512 * 256 * 2);
  const size_t o_lw2 = alloc((size_t)512 * 256 * 2);
  const size_t o_lw3 = alloc((size_t)512 * 256 * 2);
  const size_t o_ss  = alloc((size_t)4 * 256 * 4);
  const size_t o_B1  = alloc(SZ_LF);
  const size_t o_B2  = alloc(SZ_CNV);
  const size_t o_B3  = alloc(SZ_CNV);
  const size_t o_lfL = alloc(SZ_LF);
  const size_t o_lfR = alloc(SZ_LF);
  const size_t o_le  = alloc(SZ_BT);
  const size_t o_re  = alloc(SZ_BT);
  const size_t o_h1L = alloc(SZ_BT);
  const size_t o_h1R = alloc(SZ_BT);
  const size_t o_hoL = alloc(SZ_BT);
  const size_t o_hoR = alloc(SZ_BT);
  const size_t o_t1  = alloc(SZ_BT);
  const size_t o_y32 = alloc((size_t)NBT * 128 * 4);
  const size_t NEED = off;
  if (ws_size < NEED) {   // graceful diagnostic: zero output, clean absmax-fail
    zero_out<<<(out_size + 255) / 256, 256, 0, stream>>>((float*)d_out, out_size);
    return;
  }
  auto P = [&](size_t o_) { return (void*)(base + o_); };

  auto gemm = [&](const void* A, const void* Bt, void* c32, void* co,
                  const void* bias_, const void* sc_, const void* sh_,
                  long M, int N, int K, int lda, int flags) {
    dim3 g((unsigned)(N / 128), (unsigned)((M + 127) / 128));
    gemm_bf16<<<g, 256, 0, stream>>>(A, (const bf16*)Bt, (float*)c32, (bf16*)co,
                                     (const float*)bias_, (const float*)sc_,
                                     (const float*)sh_, (int)M, N, K, lda, flags);
  };
  auto cvt = [&](const float* s, void* d, long n) {
    cvt_k<<<(unsigned)((n + 255) / 256), 256, 0, stream>>>(s, (bf16*)d, n);
  };

  // ---- weight prep ----
  prep_gatW<<<512, 256, 0, stream>>>(gW[0], (bf16*)P(o_w1t), 512);
  prep_gatW<<<256, 256, 0, stream>>>(gW[1], (bf16*)P(o_w2t), 256);
  prep_convw<<<768, 256, 0, stream>>>(cw_[0], (bf16*)P(o_cw1));
  prep_convw<<<768, 256, 0, stream>>>(cw_[1], (bf16*)P(o_cw2));
  cvt(wq, P(o_wq), 65536); cvt(wk, P(o_wk), 65536);
  cvt(wv, P(o_wv), 65536); cvt(wo, P(o_wo), 65536);
  cvt(o1w, P(o_o1w), 65536);
  cvt(Lwih[0][0], P(o_lw0), 131072); cvt(Lwih[0][1], P(o_lw1), 131072);
  cvt(Lwih[1][0], P(o_lw2), 131072); cvt(Lwih[1][1], P(o_lw3), 131072);
  prep_out2<<<128, 256, 0, stream>>>(o2w, (bf16*)P(o_o2p));
  float* sc1 = (float*)P(o_ss); float* sh1 = sc1 + 256;
  float* sc2 = sh1 + 256;       float* sh2 = sc2 + 256;
  prep_scsh<<<1, 256, 0, stream>>>(cb_[0], bng[0], bnb[0], bnm[0], bnv[0], sc1, sh1);
  prep_scsh<<<1, 256, 0, stream>>>(cb_[1], bng[1], bnb[1], bnm[1], bnv[1], sc2, sh2);

  bf16* B1 = (bf16*)P(o_B1);
  bf16* B2 = (bf16*)P(o_B2);   // guard row at row 0; conv space = B2+DD
  bf16* B3 = (bf16*)P(o_B3);
  bf16* lfb[2] = { (bf16*)P(o_lfL), (bf16*)P(o_lfR) };

  // ---- per-hand: GAT x2 -> conv x2 -> lf ----
  for (int hd = 0; hd < 2; hd++) {
    gemm(feats[hd], P(o_w1t), nullptr, B1, nullptr, nullptr, nullptr,
         NLF, 256, 512, 512, 1);                                   // A_F32
    gat_attn<<<NBT, 256, 0, stream>>>(B1, ga[0], adj, B1, 0);      // in-place
    gemm(B1, P(o_w2t), nullptr, B2, nullptr, nullptr, nullptr,
         NLF, 256, 256, 256, 0);
    pad_zero<<<336, 256, 0, stream>>>(B3 + DD);
    gat_attn<<<NBT, 256, 0, stream>>>(B2, ga[1], adj, B3 + DD, 1); // conv layout
    // conv1: single GEMM K=768 over 3 contiguous rows, fused BN+ReLU+padzero
    gemm(B3, P(o_cw1), nullptr, B2 + DD, nullptr, sc1, sh1,
         CONV_M, 256, 768, 256, 8 | 4 | 16);
    // conv2: fused BN+ReLU, write straight to lf layout
    gemm(B2, P(o_cw2), nullptr, lfb[hd], nullptr, sc2, sh2,
         CONV_M, 256, 768, 256, 8 | 4 | 32);
  }

  // ---- cross-hand MHA ----
  // pass1 a_l2r: q=lf_L, k/v=lf_R
  gemm(lfb[0], P(o_wq), nullptr, B1, bq, nullptr, nullptr, NLF, 256, 256, 256, 0);
  gemm(lfb[1], P(o_wk), nullptr, B2, bk, nullptr, nullptr, NLF, 256, 256, 256, 0);
  gemm(lfb[1], P(o_wv), nullptr, B3, bv, nullptr, nullptr, NLF, 256, 256, 256, 0);
  mha_core<<<NBT, 256, 0, stream>>>(B1, B2, B3, B1);               // O in-place
  gemm(B1, P(o_wo), nullptr, B2, bo, nullptr, nullptr, NLF, 256, 256, 256, 0);
  pool_kernel<<<NBT, 256, 0, stream>>>(lfb[1], B2, (bf16*)P(o_re)); // re = rf+0.5*a_l2r
  // pass2 a_r2l: q=lf_R, k/v=lf_L
  gemm(lfb[1], P(o_wq), nullptr, B1, bq, nullptr, nullptr, NLF, 256, 256, 256, 0);
  gemm(lfb[0], P(o_wk), nullptr, B3, bk, nullptr, nullptr, NLF, 256, 256, 256, 0);
  gemm(lfb[0], P(o_wv), nullptr, B2, bv, nullptr, nullptr, NLF, 256, 256, 256, 0);
  mha_core<<<NBT, 256, 0, stream>>>(B1, B3, B2, B1);
  gemm(B1, P(o_wo), nullptr, B3, bo, nullptr, nullptr, NLF, 256, 256, 256, 0);
  pool_kernel<<<NBT, 256, 0, stream>>>(lfb[0], B3, (bf16*)P(o_le)); // le = lf+0.5*a_r2l

  // ---- BiLSTM (xw aliases B2 region: 33.5 MB f32) ----
  float* xw = (float*)P(o_B2);
  auto xslot = [&](int h_, int d_) { return (void*)(xw + ((size_t)(h_ * 2 + d_)) * NBT * 512); };
  gemm(P(o_le), P(o_lw0), xslot(0, 0), nullptr, nullptr, nullptr, nullptr, NBT, 512, 256, 256, 2);
  gemm(P(o_le), P(o_lw1), xslot(0, 1), nullptr, nullptr, nullptr, nullptr, NBT, 512, 256, 256, 2);
  gemm(P(o_re), P(o_lw0), xslot(1, 0), nullptr, nullptr, nullptr, nullptr, NBT, 512, 256, 256, 2);
  gemm(P(o_re), P(o_lw1), xslot(1, 1), nullptr, nullptr, nullptr, nullptr, NBT, 512, 256, 256, 2);
  lstm_layer<<<32, 512, 0, stream>>>(xw, Lwhh[0][0], Lwhh[0][1],
      Lbih[0][0], Lbhh[0][0], Lbih[0][1], Lbhh[0][1],
      (bf16*)P(o_h1L), (bf16*)P(o_h1R));
  gemm(P(o_h1L), P(o_lw2), xslot(0, 0), nullptr, nullptr, nullptr, nullptr, NBT, 512, 256, 256, 2);
  gemm(P(o_h1L), P(o_lw3), xslot(0, 1), nullptr, nullptr, nullptr, nullptr, NBT, 512, 256, 256, 2);
  gemm(P(o_h1R), P(o_lw2), xslot(1, 0), nullptr, nullptr, nullptr, nullptr, NBT, 512, 256, 256, 2);
  gemm(P(o_h1R), P(o_lw3), xslot(1, 1), nullptr, nullptr, nullptr, nullptr, NBT, 512, 256, 256, 2);
  lstm_layer<<<32, 512, 0, stream>>>(xw, Lwhh[1][0], Lwhh[1][1],
      Lbih[1][0], Lbhh[1][0], Lbih[1][1], Lbhh[1][1],
      (bf16*)P(o_hoL), (bf16*)P(o_hoR));

  // ---- heads + visibility ----
  for (int hd = 0; hd < 2; hd++) {
    const void* hin = hd ? P(o_hoR) : P(o_hoL);
    gemm(hin, P(o_o1w), nullptr, P(o_t1), o1b, nullptr, nullptr, NBT, 256, 256, 256, 4);
    gemm(P(o_t1), P(o_o2p), P(o_y32), nullptr, nullptr, nullptr, nullptr, NBT, 128, 256, 256, 2);
    finalize_k<<<(NBT * 63 + 255) / 256, 256, 0, stream>>>(
        (const float*)P(o_y32), o2b, vis, (float*)d_out + (size_t)hd * NBT * 63);
  }
}